// Round 1
// baseline (293.777 us; speedup 1.0000x reference)
//
#include <hip/hip_runtime.h>

// L_p[b,d] = sum_e (sum_f Theta[d,f] * X[b,f,e])^2
// B=16384, F=50, E=64, D=128, fp32 in/out; bf16 MFMA compute.
//
// Per block: NB=8 batch rows. X_b staged global->LDS (transposed to [e][f] bf16,
// row stride FS=72 shorts: 16B-aligned b128 reads, bank-uniform 8/bank minimum).
// STAGING (v2): thread tau<192 owns a 4f x 4e tile (f0=4*(tau>>4), e0=4*(tau&15)):
//   4 x global_load_dwordx4 (contiguous e) -> in-register 4x4 transpose during
//   f32->bf16 cvt -> 4 x ds_write_b64 rows e0..e0+3 cols f0..f0+3.
//   tau in [192,224): f=48,49 via 1 x dwordx4 + 4 scalar b16 writes.
//   f in [50,64) zeroed once at init (read by ks=1 A-frags, never re-written).
// SOFTWARE PIPELINE (load->use distance = 1 iteration) to bury HBM latency:
//   iter ib: load_regs(b+2) [no wait] ; compute(b) ; cvt+ds_write(b+1) ; barrier
// MFMA orientation (mfma_f32_16x16x32_bf16):
//   A[m=e(lane&15)][k=f(quad*8+j)]  <- ds_read_b128 from LDS (shared by 4 waves)
//   B[k=f][n=d(lane&15)]            <- Theta, preloaded in regs (wave owns 32 d's)
//   C/D: col(lane&15)=d, row(quad*4+reg)=e -> squared-sum = 32 fma + 2 shfl_xor.

#define NB 8
constexpr int kF  = 50;
constexpr int kE  = 64;
constexpr int kD  = 128;
constexpr int kFE = kF * kE;  // 3200
constexpr int FS  = 72;       // LDS row stride in shorts (bf16)

typedef __attribute__((ext_vector_type(8))) short short8;
typedef __attribute__((ext_vector_type(4))) short bf16x4;
typedef __attribute__((ext_vector_type(4))) float f32x4;

__device__ __forceinline__ short f2bf(float f) {
  // round-to-nearest-even fp32 -> bf16
  unsigned u = __float_as_uint(f);
  u += 0x7FFFu + ((u >> 16) & 1u);
  return (short)(u >> 16);
}

__global__ __launch_bounds__(256, 4) void ip_kernel(
    const float* __restrict__ X, const float* __restrict__ Th,
    float* __restrict__ out) {
  __shared__ __align__(16) short lds[2][kE * FS];  // 2 x 9216 shorts = 18432 B

  const int tid  = threadIdx.x;
  const int wid  = tid >> 6;   // wave id: owns d in [32*wid,+32)
  const int lane = tid & 63;
  const int q    = lane >> 4;  // quad
  const int m16  = lane & 15;

  // ---- staging role: tile (f0 = 4*fblk, e0) ----
  const int fblk = tid >> 4;        // 0..15; <12 = main tiles, 12..13 = f 48/49
  const int e0   = 4 * (tid & 15);  // 0,4,...,60

  // ---- zero tail f in [50,64) once (read by ks=1 A-frags, never re-written) ----
  for (int i = tid; i < kE * 14 * 2; i += 256) {
    const int buf = (i >= kE * 14) ? 1 : 0;
    const int r = i - buf * kE * 14;
    lds[buf][(r / 14) * FS + 50 + (r % 14)] = 0;
  }

  // ---- Theta B-frags: th[dt][ks][j] = Theta[d0+16dt+m16][32ks+8q+j], 0 if f>=50 ----
  short8 th[2][2];
  const int d0 = wid * 32;
#pragma unroll
  for (int dt = 0; dt < 2; ++dt) {
    const float* trow = Th + (size_t)(d0 + dt * 16 + m16) * kF;
#pragma unroll
    for (int ks = 0; ks < 2; ++ks) {
      short8 v;
#pragma unroll
      for (int j = 0; j < 8; ++j) {
        const int k = ks * 32 + q * 8 + j;
        v[j] = (k < kF) ? f2bf(trow[k]) : (short)0;
      }
      th[dt][ks] = v;
    }
  }

  const int b0 = blockIdx.x * NB;

  // Two in-flight register sets: xr[set][j] = X[b][f0+j][e0..e0+3] (main tiles);
  // remainder threads use xr[set][0] = X[b][48+(fblk-12)][e0..e0+3].
  f32x4 xr[2][4];

  auto load_regs = [&](int set, int b) {
    const float* xb = X + (size_t)b * kFE;
    if (fblk < 12) {
      const float* p = xb + fblk * 4 * kE + e0;
#pragma unroll
      for (int j = 0; j < 4; ++j)
        xr[set][j] = *reinterpret_cast<const f32x4*>(p + j * kE);
    } else if (fblk < 14) {
      xr[set][0] = *reinterpret_cast<const f32x4*>(xb + (36 + fblk) * kE + e0);
    }
  };

  auto cvt_write = [&](int set, int buf) {
    if (fblk < 12) {
      // 4x4 register transpose: row e0+k gets cols f0..f0+3 as one b64 write
#pragma unroll
      for (int k = 0; k < 4; ++k) {
        bf16x4 w;
#pragma unroll
        for (int j = 0; j < 4; ++j) w[j] = f2bf(xr[set][j][k]);
        *reinterpret_cast<bf16x4*>(&lds[buf][(e0 + k) * FS + fblk * 4]) = w;
      }
    } else if (fblk < 14) {
      const int f = 36 + fblk;  // 48 or 49
#pragma unroll
      for (int k = 0; k < 4; ++k)
        lds[buf][(e0 + k) * FS + f] = f2bf(xr[set][0][k]);
    }
  };

  // ---- prologue: fill buf0 with b0, issue loads for b0+1 ----
  load_regs(0, b0);
  cvt_write(0, 0);
  load_regs(1, b0 + 1);
  __syncthreads();

#pragma unroll
  for (int ib = 0; ib < NB; ++ib) {
    const int cur = ib & 1;
    const int b = b0 + ib;

    // issue loads for b+2 (consumed next iteration; overwrites set consumed last iter)
    if (ib + 2 < NB) load_regs(cur, b + 2);

    // ---- compute from lds[cur]: 8 ds_read_b128 + 16 MFMA ----
    const short* L = &lds[cur][m16 * FS + q * 8];
    f32x4 acc[4][2];
#pragma unroll
    for (int et = 0; et < 4; ++et)
#pragma unroll
      for (int dt = 0; dt < 2; ++dt) acc[et][dt] = (f32x4){0.f, 0.f, 0.f, 0.f};

#pragma unroll
    for (int et = 0; et < 4; ++et) {
      const short8 a0 = *reinterpret_cast<const short8*>(&L[et * 16 * FS]);
      const short8 a1 = *reinterpret_cast<const short8*>(&L[et * 16 * FS + 32]);
#pragma unroll
      for (int dt = 0; dt < 2; ++dt) {
        acc[et][dt] = __builtin_amdgcn_mfma_f32_16x16x32_bf16(a0, th[dt][0], acc[et][dt], 0, 0, 0);
        acc[et][dt] = __builtin_amdgcn_mfma_f32_16x16x32_bf16(a1, th[dt][1], acc[et][dt], 0, 0, 0);
      }
    }

    // ---- epilogue: L_p[b,d] = sum_e proj^2 ----
    float sv[2];
#pragma unroll
    for (int dt = 0; dt < 2; ++dt) {
      float s = 0.0f;
#pragma unroll
      for (int et = 0; et < 4; ++et)
#pragma unroll
        for (int r = 0; r < 4; ++r) {
          const float p = acc[et][dt][r];
          s = fmaf(p, p, s);
        }
      s += __shfl_xor(s, 16, 64);
      s += __shfl_xor(s, 32, 64);
      sv[dt] = s;
    }
    if (lane < 32) out[(size_t)b * kD + d0 + lane] = (lane < 16) ? sv[0] : sv[1];

    // ---- stage b+1 into the other buffer (loads issued one iteration ago) ----
    if (ib + 1 < NB) cvt_write(cur ^ 1, cur ^ 1);

    __syncthreads();
  }
}

extern "C" void kernel_launch(void* const* d_in, const int* in_sizes, int n_in,
                              void* d_out, int out_size, void* d_ws, size_t ws_size,
                              hipStream_t stream) {
  const float* X  = (const float*)d_in[0];  // [16384, 50, 64] fp32
  const float* Th = (const float*)d_in[1];  // [128, 50] fp32
  float* out = (float*)d_out;               // [16384, 128] fp32
  ip_kernel<<<dim3(16384 / NB), dim3(256), 0, stream>>>(X, Th, out);
}